// Round 1
// baseline (233.595 us; speedup 1.0000x reference)
//
#include <hip/hip_runtime.h>
#include <math.h>

// ---------------- types / helpers ----------------
typedef float f32x4 __attribute__((ext_vector_type(4)));
typedef __bf16 bf16x8 __attribute__((ext_vector_type(8)));
typedef unsigned short ushort_t;

#define MFMA16(a, b, c) __builtin_amdgcn_mfma_f32_16x16x32_bf16((a), (b), (c), 0, 0, 0)

static __device__ __forceinline__ ushort_t f2bf(float f) {
  union { float f; unsigned u; } v; v.f = f;
  unsigned u = v.u;
  return (ushort_t)((u + 0x7FFFu + ((u >> 16) & 1u)) >> 16);  // RNE
}
static __device__ __forceinline__ float bf2f(ushort_t h) {
  union { unsigned u; float f; } v; v.u = ((unsigned)h) << 16;
  return v.f;
}
// async global->LDS, 16B per lane; lds pointer must be wave-uniform (dest = base + lane*16)
static __device__ __forceinline__ void gl_lds16(const void* g, void* lds_uniform) {
  __builtin_amdgcn_global_load_lds(
      (const __attribute__((address_space(1))) unsigned int*)g,
      (__attribute__((address_space(3))) unsigned int*)lds_uniform, 16, 0, 0);
}

// ---------------- RoPE cos/sin table (double precision, matches np ref) ----------------
__global__ void rope_table(float2* __restrict__ cs) {
  int idx = blockIdx.x * 256 + threadIdx.x;   // 4096*32 entries
  int pos = idx >> 5, i = idx & 31;
  double inv = exp2(-(double)i * 0.41524101186092029);  // log2(10000)/32
  double th = (double)pos * inv;
  double s, c;
  sincos(th, &s, &c);
  cs[idx] = make_float2((float)c, (float)s);
}

// ---------------- fp32 -> bf16 cast ----------------
__global__ void cast_bf16(const float* __restrict__ in, ushort_t* __restrict__ out, int n4) {
  int i = blockIdx.x * 256 + threadIdx.x;
  if (i >= n4) return;
  f32x4 v = ((const f32x4*)in)[i];
  ushort4 o;
  o.x = f2bf(v.x); o.y = f2bf(v.y); o.z = f2bf(v.z); o.w = f2bf(v.w);
  ((ushort4*)out)[i] = o;
}

// ---------------- m97-style NT GEMM: C[m][n] = sum_k A[m][k]*W[n][k] ----------------
// A: MxK bf16 row-major, W: NxK bf16 row-major. OUTBF=1 -> bf16 out, else fp32 out.
// grid = (M/128, N/128, nz); z selects (W,C) pair.
template <int OUTBF>
__global__ __launch_bounds__(256) void gemm_nt(
    const ushort_t* __restrict__ A,
    const ushort_t* __restrict__ W0, const ushort_t* __restrict__ W1, const ushort_t* __restrict__ W2,
    void* __restrict__ C0, void* __restrict__ C1, void* __restrict__ C2,
    int K, int N) {
  __shared__ __align__(16) ushort_t As[128 * 32];
  __shared__ __align__(16) ushort_t Bs[128 * 32];
  const int z = blockIdx.z;
  const ushort_t* W = (z == 0) ? W0 : (z == 1 ? W1 : W2);
  void* Cv = (z == 0) ? C0 : (z == 1 ? C1 : C2);

  const int t = threadIdx.x;
  const int lane = t & 63;
  const int l15 = lane & 15;
  const int quad = lane >> 4;
  const int wave = t >> 6;
  const int wm = wave & 1, wn = wave >> 1;
  const int bm = blockIdx.x, bn = blockIdx.y;

  const ushort_t* Ag = A + (size_t)(bm * 128 + (t >> 2)) * K + (t & 3) * 8;
  const ushort_t* Wg = W + (size_t)(bn * 128 + (t >> 2)) * K + (t & 3) * 8;
  char* AsB = (char*)As + (t & 192) * 16;  // wave-uniform base; lane slot = base + lane*16
  char* BsB = (char*)Bs + (t & 192) * 16;
  const size_t rK = (size_t)64 * K;

  const f32x4 zero4 = {0.f, 0.f, 0.f, 0.f};
  f32x4 acc[4][4];
#pragma unroll
  for (int i = 0; i < 4; ++i)
#pragma unroll
    for (int j = 0; j < 4; ++j) acc[i][j] = zero4;

  for (int kt = 0; kt < K; kt += 32) {
    gl_lds16(Ag + kt, AsB);
    gl_lds16(Ag + rK + kt, AsB + 4096);
    gl_lds16(Wg + kt, BsB);
    gl_lds16(Wg + rK + kt, BsB + 4096);
    __syncthreads();
    bf16x8 af[4], bf[4];
#pragma unroll
    for (int i = 0; i < 4; ++i)
      af[i] = *(const bf16x8*)&As[(wm * 64 + i * 16 + l15) * 32 + quad * 8];
#pragma unroll
    for (int j = 0; j < 4; ++j)
      bf[j] = *(const bf16x8*)&Bs[(wn * 64 + j * 16 + l15) * 32 + quad * 8];
#pragma unroll
    for (int i = 0; i < 4; ++i)
#pragma unroll
      for (int j = 0; j < 4; ++j) acc[i][j] = MFMA16(af[i], bf[j], acc[i][j]);
    __syncthreads();
  }

  const int rbase = bm * 128 + wm * 64 + quad * 4;
  const int cbase = bn * 128 + wn * 64 + l15;
#pragma unroll
  for (int i = 0; i < 4; ++i)
#pragma unroll
    for (int j = 0; j < 4; ++j)
#pragma unroll
      for (int r = 0; r < 4; ++r) {
        size_t idx = (size_t)(rbase + i * 16 + r) * N + (cbase + j * 16);
        if (OUTBF)
          ((ushort_t*)Cv)[idx] = f2bf(acc[i][j][r]);
        else
          ((float*)Cv)[idx] = acc[i][j][r];
      }
}

// ---------------- fused windowed attention ----------------
// grid = (32, 16, 2): x = window*2 + qslice, y = head, z = batch. block = 256 (4 waves).
// Block does 128 q-rows vs full 256-row window. RoPE applied on load (fp32), scale folded into Q.
static __device__ __forceinline__ void rope8(const ushort_t* __restrict__ g,
                                             ushort_t* __restrict__ lds,
                                             const float2* __restrict__ cs4, float scale) {
  uint4 raw = *(const uint4*)g;
  unsigned rw[4] = {raw.x, raw.y, raw.z, raw.w};
  ushort_t o[8];
#pragma unroll
  for (int m = 0; m < 4; ++m) {
    float x1 = bf2f((ushort_t)(rw[m] & 0xffffu));
    float x2 = bf2f((ushort_t)(rw[m] >> 16));
    float2 sc = cs4[m];
    o[2 * m]     = f2bf((x1 * sc.x - x2 * sc.y) * scale);
    o[2 * m + 1] = f2bf((x1 * sc.y + x2 * sc.x) * scale);
  }
  uint4 w;
  w.x = (unsigned)o[0] | ((unsigned)o[1] << 16);
  w.y = (unsigned)o[2] | ((unsigned)o[3] << 16);
  w.z = (unsigned)o[4] | ((unsigned)o[5] << 16);
  w.w = (unsigned)o[6] | ((unsigned)o[7] << 16);
  *(uint4*)lds = w;  // ds_write_b128
}

__global__ __launch_bounds__(256, 2) void attn(
    const ushort_t* __restrict__ Qb, const ushort_t* __restrict__ Kb,
    const ushort_t* __restrict__ Vb, ushort_t* __restrict__ Yb,
    const float2* __restrict__ cs) {
  // 55296 B of LDS, phase-overlaid:
  //   phase 1/2: Qs[128][72] @0, Ks[256][72] @9216
  //   phase 3:   Vt[64][264] @0, Pc[128][72] @16896
  __shared__ __align__(16) ushort_t smem[27648];
  ushort_t* Qs = smem;
  ushort_t* Ks = smem + 9216;
  ushort_t* Vt = smem;
  ushort_t* Pc = smem + 16896;

  const int t = threadIdx.x;
  const int lane = t & 63, wave = t >> 6;
  const int l15 = lane & 15, quad = lane >> 4;
  const int win = blockIdx.x >> 1, slice = blockIdx.x & 1;
  const int h = blockIdx.y, b = blockIdx.z;
  const int kBase = win * 256, qBase = kBase + slice * 128;
  const size_t gbase = ((size_t)b * 4096) * 1024 + h * 64;

  const int sr = t >> 3;       // 0..31: staging row
  const int c0 = (t & 7) * 8;  // staging col (8 bf16 per thread)

  // ---- stage Q (rope * 1/sqrt(64)) and K (rope) ----
#pragma unroll
  for (int p = 0; p < 4; ++p) {
    int r = p * 32 + sr;
    rope8(Qb + gbase + (size_t)(qBase + r) * 1024 + c0, Qs + r * 72 + c0,
          cs + (qBase + r) * 32 + (c0 >> 1), 0.125f);
  }
#pragma unroll
  for (int p = 0; p < 8; ++p) {
    int r = p * 32 + sr;
    rope8(Kb + gbase + (size_t)(kBase + r) * 1024 + c0, Ks + r * 72 + c0,
          cs + (kBase + r) * 32 + (c0 >> 1), 1.0f);
  }
  __syncthreads();

  // ---- scores: each wave 32 q-rows x 256 cols in regs ----
  const int qw = wave * 32;
  const f32x4 zero4 = {0.f, 0.f, 0.f, 0.f};
  f32x4 S[2][16];
#pragma unroll
  for (int i = 0; i < 2; ++i)
#pragma unroll
    for (int j = 0; j < 16; ++j) S[i][j] = zero4;
#pragma unroll
  for (int ks = 0; ks < 2; ++ks) {
    bf16x8 a0 = *(const bf16x8*)&Qs[(qw + l15) * 72 + ks * 32 + quad * 8];
    bf16x8 a1 = *(const bf16x8*)&Qs[(qw + 16 + l15) * 72 + ks * 32 + quad * 8];
#pragma unroll
    for (int j = 0; j < 16; ++j) {
      bf16x8 bk = *(const bf16x8*)&Ks[(j * 16 + l15) * 72 + ks * 32 + quad * 8];
      S[0][j] = MFMA16(a0, bk, S[0][j]);
      S[1][j] = MFMA16(a1, bk, S[1][j]);
    }
  }

  // ---- softmax (fp32, rows live in 16-lane quads) ----
  float linv[2][4];
#pragma unroll
  for (int i = 0; i < 2; ++i)
#pragma unroll
    for (int r = 0; r < 4; ++r) {
      float mx = S[i][0][r];
#pragma unroll
      for (int j = 1; j < 16; ++j) mx = fmaxf(mx, S[i][j][r]);
      mx = fmaxf(mx, __shfl_xor(mx, 1));
      mx = fmaxf(mx, __shfl_xor(mx, 2));
      mx = fmaxf(mx, __shfl_xor(mx, 4));
      mx = fmaxf(mx, __shfl_xor(mx, 8));
      float sum = 0.f;
#pragma unroll
      for (int j = 0; j < 16; ++j) {
        float e = __expf(S[i][j][r] - mx);
        S[i][j][r] = e;
        sum += e;
      }
      sum += __shfl_xor(sum, 1);
      sum += __shfl_xor(sum, 2);
      sum += __shfl_xor(sum, 4);
      sum += __shfl_xor(sum, 8);
      linv[i][r] = 1.0f / sum;
    }
  __syncthreads();  // everyone done reading Qs/Ks; overlay region becomes Vt/Pc

  // ---- stage V transposed: Vt[d][k] (lane-staggered writes -> conflict-free) ----
#pragma unroll
  for (int p = 0; p < 8; ++p) {
    int k = p * 32 + sr;
    uint4 raw = *(const uint4*)(Vb + gbase + (size_t)(kBase + k) * 1024 + c0);
    ushort_t vv[8];
    vv[0] = raw.x & 0xffffu; vv[1] = raw.x >> 16;
    vv[2] = raw.y & 0xffffu; vv[3] = raw.y >> 16;
    vv[4] = raw.z & 0xffffu; vv[5] = raw.z >> 16;
    vv[6] = raw.w & 0xffffu; vv[7] = raw.w >> 16;
#pragma unroll
    for (int e = 0; e < 8; ++e) {
      int ee = (e + (t & 7)) & 7;
      Vt[(c0 + ee) * 264 + k] = vv[ee];
    }
  }

  // P chunk writer: C-layout -> row-major bf16 in LDS (A-layout for PV)
  auto writeP = [&](int kc) {
#pragma unroll
    for (int i = 0; i < 2; ++i)
#pragma unroll
      for (int jj = 0; jj < 4; ++jj) {
        int j = kc * 4 + jj;
#pragma unroll
        for (int r = 0; r < 4; ++r)
          Pc[(qw + i * 16 + quad * 4 + r) * 72 + jj * 16 + l15] = f2bf(S[i][j][r]);
      }
  };

  writeP(0);
  __syncthreads();

  f32x4 O[2][4];
#pragma unroll
  for (int i = 0; i < 2; ++i)
#pragma unroll
    for (int jd = 0; jd < 4; ++jd) O[i][jd] = zero4;

  for (int kc = 0; kc < 4; ++kc) {
#pragma unroll
    for (int ks = 0; ks < 2; ++ks) {
      bf16x8 a0 = *(const bf16x8*)&Pc[(qw + l15) * 72 + ks * 32 + quad * 8];
      bf16x8 a1 = *(const bf16x8*)&Pc[(qw + 16 + l15) * 72 + ks * 32 + quad * 8];
#pragma unroll
      for (int jd = 0; jd < 4; ++jd) {
        bf16x8 bv = *(const bf16x8*)&Vt[(jd * 16 + l15) * 264 + kc * 64 + ks * 32 + quad * 8];
        O[0][jd] = MFMA16(a0, bv, O[0][jd]);
        O[1][jd] = MFMA16(a1, bv, O[1][jd]);
      }
    }
    if (kc < 3) {
      __syncthreads();
      writeP(kc + 1);
      __syncthreads();
    }
  }

  // ---- epilogue: normalize, write Y in (B,T,C) bf16 ----
#pragma unroll
  for (int i = 0; i < 2; ++i)
#pragma unroll
    for (int jd = 0; jd < 4; ++jd)
#pragma unroll
      for (int r = 0; r < 4; ++r) {
        int row = qBase + qw + i * 16 + quad * 4 + r;
        int col = jd * 16 + l15;
        Yb[gbase + (size_t)row * 1024 + col] = f2bf(O[i][jd][r] * linv[i][r]);
      }
}

// ---------------- launch ----------------
extern "C" void kernel_launch(void* const* d_in, const int* in_sizes, int n_in,
                              void* d_out, int out_size, void* d_ws, size_t ws_size,
                              hipStream_t stream) {
  (void)in_sizes; (void)n_in; (void)out_size; (void)ws_size;
  const float* x  = (const float*)d_in[0];
  const float* wq = (const float*)d_in[1];
  const float* wk = (const float*)d_in[2];
  const float* wv = (const float*)d_in[3];
  const float* wo = (const float*)d_in[4];

  char* ws = (char*)d_ws;
  // workspace layout (bytes): Xb 16M | Wq..Wo 4x2M | Qb 16M | Kb 16M | Vb 16M | Yb 16M | cs 1M
  ushort_t* Xb  = (ushort_t*)(ws);
  ushort_t* Wqb = (ushort_t*)(ws + 16777216);
  ushort_t* Wkb = Wqb + 1048576;
  ushort_t* Wvb = Wkb + 1048576;
  ushort_t* Wob = Wvb + 1048576;
  ushort_t* Qb  = (ushort_t*)(ws + 25165824);
  ushort_t* Kb  = Qb + 8388608;
  ushort_t* Vb  = Kb + 8388608;
  ushort_t* Yb  = Vb + 8388608;
  float2*   cs  = (float2*)(ws + 92274688);

  rope_table<<<dim3(512), dim3(256), 0, stream>>>(cs);
  cast_bf16<<<dim3(8192), dim3(256), 0, stream>>>(x, Xb, 2097152);
  cast_bf16<<<dim3(1024), dim3(256), 0, stream>>>(wq, Wqb, 262144);
  cast_bf16<<<dim3(1024), dim3(256), 0, stream>>>(wk, Wkb, 262144);
  cast_bf16<<<dim3(1024), dim3(256), 0, stream>>>(wv, Wvb, 262144);
  cast_bf16<<<dim3(1024), dim3(256), 0, stream>>>(wo, Wob, 262144);

  gemm_nt<1><<<dim3(64, 8, 3), dim3(256), 0, stream>>>(
      Xb, Wqb, Wkb, Wvb, (void*)Qb, (void*)Kb, (void*)Vb, 1024, 1024);

  attn<<<dim3(32, 16, 2), dim3(256), 0, stream>>>(Qb, Kb, Vb, Yb, cs);

  gemm_nt<0><<<dim3(64, 8, 1), dim3(256), 0, stream>>>(
      Yb, Wob, Wob, Wob, d_out, d_out, d_out, 1024, 1024);
}

// Round 2
// 214.256 us; speedup vs baseline: 1.0903x; 1.0903x over previous
//
#include <hip/hip_runtime.h>
#include <math.h>

// ---------------- types / helpers ----------------
typedef float f32x4 __attribute__((ext_vector_type(4)));
typedef __bf16 bf16x8 __attribute__((ext_vector_type(8)));
typedef unsigned short ushort_t;

#define MFMA16(a, b, c) __builtin_amdgcn_mfma_f32_16x16x32_bf16((a), (b), (c), 0, 0, 0)

static __device__ __forceinline__ ushort_t f2bf(float f) {
  union { float f; unsigned u; } v; v.f = f;
  unsigned u = v.u;
  return (ushort_t)((u + 0x7FFFu + ((u >> 16) & 1u)) >> 16);  // RNE
}
static __device__ __forceinline__ float bf2f(ushort_t h) {
  union { unsigned u; float f; } v; v.u = ((unsigned)h) << 16;
  return v.f;
}
// async global->LDS, 16B per lane; lds pointer must be wave-uniform (dest = base + lane*16)
static __device__ __forceinline__ void gl_lds16(const void* g, void* lds_uniform) {
  __builtin_amdgcn_global_load_lds(
      (const __attribute__((address_space(1))) unsigned int*)g,
      (__attribute__((address_space(3))) unsigned int*)lds_uniform, 16, 0, 0);
}

// ---------------- fused prep: x/w casts + RoPE table (1 launch instead of 5) ----------
// blocks [0,8192): x cast (2M float4); [8192,12288): 4 weights (1024 blocks each);
// [12288,12800): rope table 4096*32 entries.
__global__ void prep(const float* __restrict__ x,
                     const float* __restrict__ wq, const float* __restrict__ wk,
                     const float* __restrict__ wv, const float* __restrict__ wo,
                     ushort_t* __restrict__ Xb, ushort_t* __restrict__ Wqb,
                     ushort_t* __restrict__ Wkb, ushort_t* __restrict__ Wvb,
                     ushort_t* __restrict__ Wob, float2* __restrict__ cs) {
  const int bid = blockIdx.x;
  if (bid < 12288) {
    const float* src;
    ushort_t* dst;
    int i;
    if (bid < 8192) {
      src = x; dst = Xb;
      i = bid * 256 + threadIdx.x;
    } else {
      const int wi = (bid - 8192) >> 10;
      src = (wi == 0) ? wq : (wi == 1) ? wk : (wi == 2) ? wv : wo;
      dst = (wi == 0) ? Wqb : (wi == 1) ? Wkb : (wi == 2) ? Wvb : Wob;
      i = ((bid - 8192) & 1023) * 256 + threadIdx.x;
    }
    f32x4 v = ((const f32x4*)src)[i];
    ushort4 o;
    o.x = f2bf(v.x); o.y = f2bf(v.y); o.z = f2bf(v.z); o.w = f2bf(v.w);
    ((ushort4*)dst)[i] = o;
  } else {
    int idx = (bid - 12288) * 256 + threadIdx.x;  // 4096*32 entries
    int pos = idx >> 5, i = idx & 31;
    double inv = exp2(-(double)i * 0.41524101186092029);  // log2(10000)/32
    double th = (double)pos * inv;
    double s, c;
    sincos(th, &s, &c);
    cs[idx] = make_float2((float)c, (float)s);
  }
}

// ---------------- NT GEMM, BK=64, XOR-swizzled LDS (conflict-free b128 reads) --------
// C[m][n] = sum_k A[m][k]*W[n][k]. A: MxK bf16 rm, W: NxK bf16 rm.
// LDS slot (row, chunk c) holds global chunk c ^ (row&7); readers apply same XOR.
// Row stride 128B == 32 banks, swizzle spreads the 16B spans uniformly (8x4B/bank).
template <int OUTBF>
__global__ __launch_bounds__(256) void gemm_nt(
    const ushort_t* __restrict__ A,
    const ushort_t* __restrict__ W0, const ushort_t* __restrict__ W1, const ushort_t* __restrict__ W2,
    void* __restrict__ C0, void* __restrict__ C1, void* __restrict__ C2,
    int K, int N) {
  __shared__ __align__(16) ushort_t As[128 * 64];
  __shared__ __align__(16) ushort_t Bs[128 * 64];
  const int z = blockIdx.z;
  const ushort_t* W = (z == 0) ? W0 : (z == 1 ? W1 : W2);
  void* Cv = (z == 0) ? C0 : (z == 1 ? C1 : C2);

  const int t = threadIdx.x;
  const int lane = t & 63;
  const int l15 = lane & 15;
  const int quad = lane >> 4;
  const int wave = t >> 6;
  const int wm = wave & 1, wn = wave >> 1;
  const int bm = blockIdx.x, bn = blockIdx.y;

  // staging: thread t -> row t>>3, LDS chunk t&7, global chunk (t&7)^(row&7)
  const int srow = t >> 3;
  const int schunk = (t & 7) ^ (srow & 7);
  const ushort_t* Ag = A + (size_t)(bm * 128 + srow) * K + schunk * 8;
  const ushort_t* Wg = W + (size_t)(bn * 128 + srow) * K + schunk * 8;
  char* AsB = (char*)As + (t & 192) * 16;  // wave-uniform; lane slot = base + lane*16
  char* BsB = (char*)Bs + (t & 192) * 16;
  const size_t rK = (size_t)32 * K;

  const f32x4 zero4 = {0.f, 0.f, 0.f, 0.f};
  f32x4 acc[4][4];
#pragma unroll
  for (int i = 0; i < 4; ++i)
#pragma unroll
    for (int j = 0; j < 4; ++j) acc[i][j] = zero4;

  for (int kt = 0; kt < K; kt += 64) {
#pragma unroll
    for (int p = 0; p < 4; ++p) {
      gl_lds16(Ag + p * rK + kt, AsB + p * 4096);
      gl_lds16(Wg + p * rK + kt, BsB + p * 4096);
    }
    __syncthreads();
#pragma unroll
    for (int ks = 0; ks < 2; ++ks) {
      bf16x8 af[4], bfr[4];
#pragma unroll
      for (int i = 0; i < 4; ++i) {
        const int r = wm * 64 + i * 16 + l15;
        af[i] = *(const bf16x8*)&As[r * 64 + (((ks * 4 + quad) ^ (r & 7)) * 8)];
      }
#pragma unroll
      for (int j = 0; j < 4; ++j) {
        const int r = wn * 64 + j * 16 + l15;
        bfr[j] = *(const bf16x8*)&Bs[r * 64 + (((ks * 4 + quad) ^ (r & 7)) * 8)];
      }
#pragma unroll
      for (int i = 0; i < 4; ++i)
#pragma unroll
        for (int j = 0; j < 4; ++j) acc[i][j] = MFMA16(af[i], bfr[j], acc[i][j]);
    }
    __syncthreads();
  }

  const int rbase = bm * 128 + wm * 64 + quad * 4;
  const int cbase = bn * 128 + wn * 64 + l15;
#pragma unroll
  for (int i = 0; i < 4; ++i)
#pragma unroll
    for (int j = 0; j < 4; ++j)
#pragma unroll
      for (int r = 0; r < 4; ++r) {
        size_t idx = (size_t)(rbase + i * 16 + r) * N + (cbase + j * 16);
        if (OUTBF)
          ((ushort_t*)Cv)[idx] = f2bf(acc[i][j][r]);
        else
          ((float*)Cv)[idx] = acc[i][j][r];
      }
}

// ---------------- fused windowed attention ----------------
// grid = (32, 16, 2): x = window*2 + qslice, y = head, z = batch. block = 256 (4 waves).
// Block does 128 q-rows vs full 256-row window. RoPE applied on load (fp32), scale folded into Q.
static __device__ __forceinline__ void rope8(const ushort_t* __restrict__ g,
                                             ushort_t* __restrict__ lds,
                                             const float2* __restrict__ cs4, float scale) {
  uint4 raw = *(const uint4*)g;
  unsigned rw[4] = {raw.x, raw.y, raw.z, raw.w};
  ushort_t o[8];
#pragma unroll
  for (int m = 0; m < 4; ++m) {
    float x1 = bf2f((ushort_t)(rw[m] & 0xffffu));
    float x2 = bf2f((ushort_t)(rw[m] >> 16));
    float2 sc = cs4[m];
    o[2 * m]     = f2bf((x1 * sc.x - x2 * sc.y) * scale);
    o[2 * m + 1] = f2bf((x1 * sc.y + x2 * sc.x) * scale);
  }
  uint4 w;
  w.x = (unsigned)o[0] | ((unsigned)o[1] << 16);
  w.y = (unsigned)o[2] | ((unsigned)o[3] << 16);
  w.z = (unsigned)o[4] | ((unsigned)o[5] << 16);
  w.w = (unsigned)o[6] | ((unsigned)o[7] << 16);
  *(uint4*)lds = w;  // ds_write_b128
}

__global__ __launch_bounds__(256, 2) void attn(
    const ushort_t* __restrict__ Qb, const ushort_t* __restrict__ Kb,
    const ushort_t* __restrict__ Vb, ushort_t* __restrict__ Yb,
    const float2* __restrict__ cs) {
  // 55296 B of LDS, phase-overlaid:
  //   phase 1/2: Qs[128][72] @0, Ks[256][72] @9216
  //   phase 3:   Vt[64][264] @0, Pc[128][72] @16896
  __shared__ __align__(16) ushort_t smem[27648];
  ushort_t* Qs = smem;
  ushort_t* Ks = smem + 9216;
  ushort_t* Vt = smem;
  ushort_t* Pc = smem + 16896;

  const int t = threadIdx.x;
  const int lane = t & 63, wave = t >> 6;
  const int l15 = lane & 15, quad = lane >> 4;
  const int win = blockIdx.x >> 1, slice = blockIdx.x & 1;
  const int h = blockIdx.y, b = blockIdx.z;
  const int kBase = win * 256, qBase = kBase + slice * 128;
  const size_t gbase = ((size_t)b * 4096) * 1024 + h * 64;

  const int sr = t >> 3;       // 0..31: staging row
  const int c0 = (t & 7) * 8;  // staging col (8 bf16 per thread)

  // ---- stage Q (rope * 1/sqrt(64)) and K (rope) ----
#pragma unroll
  for (int p = 0; p < 4; ++p) {
    int r = p * 32 + sr;
    rope8(Qb + gbase + (size_t)(qBase + r) * 1024 + c0, Qs + r * 72 + c0,
          cs + (qBase + r) * 32 + (c0 >> 1), 0.125f);
  }
#pragma unroll
  for (int p = 0; p < 8; ++p) {
    int r = p * 32 + sr;
    rope8(Kb + gbase + (size_t)(kBase + r) * 1024 + c0, Ks + r * 72 + c0,
          cs + (kBase + r) * 32 + (c0 >> 1), 1.0f);
  }
  __syncthreads();

  // ---- scores: each wave 32 q-rows x 256 cols in regs ----
  const int qw = wave * 32;
  const f32x4 zero4 = {0.f, 0.f, 0.f, 0.f};
  f32x4 S[2][16];
#pragma unroll
  for (int i = 0; i < 2; ++i)
#pragma unroll
    for (int j = 0; j < 16; ++j) S[i][j] = zero4;
#pragma unroll
  for (int ks = 0; ks < 2; ++ks) {
    bf16x8 a0 = *(const bf16x8*)&Qs[(qw + l15) * 72 + ks * 32 + quad * 8];
    bf16x8 a1 = *(const bf16x8*)&Qs[(qw + 16 + l15) * 72 + ks * 32 + quad * 8];
#pragma unroll
    for (int j = 0; j < 16; ++j) {
      bf16x8 bk = *(const bf16x8*)&Ks[(j * 16 + l15) * 72 + ks * 32 + quad * 8];
      S[0][j] = MFMA16(a0, bk, S[0][j]);
      S[1][j] = MFMA16(a1, bk, S[1][j]);
    }
  }

  // ---- softmax (fp32, rows live in 16-lane quads) ----
  float linv[2][4];
#pragma unroll
  for (int i = 0; i < 2; ++i)
#pragma unroll
    for (int r = 0; r < 4; ++r) {
      float mx = S[i][0][r];
#pragma unroll
      for (int j = 1; j < 16; ++j) mx = fmaxf(mx, S[i][j][r]);
      mx = fmaxf(mx, __shfl_xor(mx, 1));
      mx = fmaxf(mx, __shfl_xor(mx, 2));
      mx = fmaxf(mx, __shfl_xor(mx, 4));
      mx = fmaxf(mx, __shfl_xor(mx, 8));
      float sum = 0.f;
#pragma unroll
      for (int j = 0; j < 16; ++j) {
        float e = __expf(S[i][j][r] - mx);
        S[i][j][r] = e;
        sum += e;
      }
      sum += __shfl_xor(sum, 1);
      sum += __shfl_xor(sum, 2);
      sum += __shfl_xor(sum, 4);
      sum += __shfl_xor(sum, 8);
      linv[i][r] = 1.0f / sum;
    }
  __syncthreads();  // everyone done reading Qs/Ks; overlay region becomes Vt/Pc

  // ---- stage V transposed: Vt[d][k] (lane-staggered writes -> conflict-free) ----
#pragma unroll
  for (int p = 0; p < 8; ++p) {
    int k = p * 32 + sr;
    uint4 raw = *(const uint4*)(Vb + gbase + (size_t)(kBase + k) * 1024 + c0);
    ushort_t vv[8];
    vv[0] = raw.x & 0xffffu; vv[1] = raw.x >> 16;
    vv[2] = raw.y & 0xffffu; vv[3] = raw.y >> 16;
    vv[4] = raw.z & 0xffffu; vv[5] = raw.z >> 16;
    vv[6] = raw.w & 0xffffu; vv[7] = raw.w >> 16;
#pragma unroll
    for (int e = 0; e < 8; ++e) {
      int ee = (e + (t & 7)) & 7;
      Vt[(c0 + ee) * 264 + k] = vv[ee];
    }
  }

  // P chunk writer: C-layout -> row-major bf16 in LDS (A-layout for PV)
  auto writeP = [&](int kc) {
#pragma unroll
    for (int i = 0; i < 2; ++i)
#pragma unroll
      for (int jj = 0; jj < 4; ++jj) {
        int j = kc * 4 + jj;
#pragma unroll
        for (int r = 0; r < 4; ++r)
          Pc[(qw + i * 16 + quad * 4 + r) * 72 + jj * 16 + l15] = f2bf(S[i][j][r]);
      }
  };

  writeP(0);
  __syncthreads();

  f32x4 O[2][4];
#pragma unroll
  for (int i = 0; i < 2; ++i)
#pragma unroll
    for (int jd = 0; jd < 4; ++jd) O[i][jd] = zero4;

  for (int kc = 0; kc < 4; ++kc) {
#pragma unroll
    for (int ks = 0; ks < 2; ++ks) {
      bf16x8 a0 = *(const bf16x8*)&Pc[(qw + l15) * 72 + ks * 32 + quad * 8];
      bf16x8 a1 = *(const bf16x8*)&Pc[(qw + 16 + l15) * 72 + ks * 32 + quad * 8];
#pragma unroll
      for (int jd = 0; jd < 4; ++jd) {
        bf16x8 bv = *(const bf16x8*)&Vt[(jd * 16 + l15) * 264 + kc * 64 + ks * 32 + quad * 8];
        O[0][jd] = MFMA16(a0, bv, O[0][jd]);
        O[1][jd] = MFMA16(a1, bv, O[1][jd]);
      }
    }
    if (kc < 3) {
      __syncthreads();
      writeP(kc + 1);
      __syncthreads();
    }
  }

  // ---- epilogue: normalize, write Y in (B,T,C) bf16 ----
#pragma unroll
  for (int i = 0; i < 2; ++i)
#pragma unroll
    for (int jd = 0; jd < 4; ++jd)
#pragma unroll
      for (int r = 0; r < 4; ++r) {
        int row = qBase + qw + i * 16 + quad * 4 + r;
        int col = jd * 16 + l15;
        Yb[gbase + (size_t)row * 1024 + col] = f2bf(O[i][jd][r] * linv[i][r]);
      }
}

// ---------------- launch ----------------
extern "C" void kernel_launch(void* const* d_in, const int* in_sizes, int n_in,
                              void* d_out, int out_size, void* d_ws, size_t ws_size,
                              hipStream_t stream) {
  (void)in_sizes; (void)n_in; (void)out_size; (void)ws_size;
  const float* x  = (const float*)d_in[0];
  const float* wq = (const float*)d_in[1];
  const float* wk = (const float*)d_in[2];
  const float* wv = (const float*)d_in[3];
  const float* wo = (const float*)d_in[4];

  char* ws = (char*)d_ws;
  // workspace layout (bytes): Xb 16M | Wq..Wo 4x2M | Qb 16M | Kb 16M | Vb 16M | Yb 16M | cs 1M
  ushort_t* Xb  = (ushort_t*)(ws);
  ushort_t* Wqb = (ushort_t*)(ws + 16777216);
  ushort_t* Wkb = Wqb + 1048576;
  ushort_t* Wvb = Wkb + 1048576;
  ushort_t* Wob = Wvb + 1048576;
  ushort_t* Qb  = (ushort_t*)(ws + 25165824);
  ushort_t* Kb  = Qb + 8388608;
  ushort_t* Vb  = Kb + 8388608;
  ushort_t* Yb  = Vb + 8388608;
  float2*   cs  = (float2*)(ws + 92274688);

  prep<<<dim3(12800), dim3(256), 0, stream>>>(x, wq, wk, wv, wo,
                                              Xb, Wqb, Wkb, Wvb, Wob, cs);

  gemm_nt<1><<<dim3(64, 8, 3), dim3(256), 0, stream>>>(
      Xb, Wqb, Wkb, Wvb, (void*)Qb, (void*)Kb, (void*)Vb, 1024, 1024);

  attn<<<dim3(32, 16, 2), dim3(256), 0, stream>>>(Qb, Kb, Vb, Yb, cs);

  gemm_nt<0><<<dim3(64, 8, 1), dim3(256), 0, stream>>>(
      Yb, Wob, Wob, Wob, d_out, d_out, d_out, 1024, 1024);
}